// Round 12
// baseline (835.889 us; speedup 1.0000x reference)
//
#include <hip/hip_runtime.h>
#include <math.h>

#define BB 8
#define CC 64
#define NN 4096
#define CI 8
#define GAMMA 0.1f
// exp(s/sqrt(8)) = exp2(s * log2(e)/sqrt(8)); folded into k in qkv.
#define SCALE (1.44269504088896f * 0.35355339059327f)
#define NSPLIT 4

typedef float v4f __attribute__((ext_vector_type(4)));
typedef __bf16 bf16x8 __attribute__((ext_vector_type(8)));
typedef __bf16 bf16x4 __attribute__((ext_vector_type(4)));

__device__ __forceinline__ float fast_exp2(float x) {
    return __builtin_amdgcn_exp2f(x);
}

// R7-proven qkv. Grid (NN/32, BB); block 256 = 8 i-groups x 32 n.
// qbh[b][n][8], kbh[b][m][8] (k*SCALE), vbh[b][i][N] bf16; zeros attab[b][9][N].
__global__ __launch_bounds__(256) void qkv_kernel(
        const float* __restrict__ x,
        const float* __restrict__ Wq, const float* __restrict__ Wk,
        const float* __restrict__ Wv,
        __bf16* __restrict__ qbh, __bf16* __restrict__ kbh,
        __bf16* __restrict__ vbh, float* __restrict__ attab) {
    __shared__ float sw[3 * CI * CC];     // 6 KB: Wq | Wk*SCALE | Wv
    __shared__ unsigned short sq[32 * 8]; // bf16 tile [n_local][i]
    __shared__ unsigned short sk[32 * 8];
    const int t = threadIdx.x;
    const int i  = t >> 5;
    const int nl = t & 31;
    const int b  = blockIdx.y;
    const int n0 = blockIdx.x * 32;

    for (int idx = t; idx < CI * CC; idx += 256) {
        sw[idx]                = Wq[idx];
        sw[CI * CC + idx]      = Wk[idx] * SCALE;
        sw[2 * CI * CC + idx]  = Wv[idx];
    }
    int lin = (blockIdx.y * (NN / 32) + blockIdx.x) * 256 + t;
    for (int idx = lin; idx < BB * 9 * NN; idx += BB * NN * CI) attab[idx] = 0.f;
    __syncthreads();

    const int n = n0 + nl;
    const float* xp = x + ((size_t)b * CC) * NN + n;
    const v4f* wq4 = (const v4f*)(sw + i * CC);
    const v4f* wk4 = (const v4f*)(sw + CI * CC + i * CC);
    const v4f* wv4 = (const v4f*)(sw + 2 * CI * CC + i * CC);
    float qa = 0.f, ka = 0.f, va = 0.f;
#pragma unroll 4
    for (int c4 = 0; c4 < CC / 4; ++c4) {
        v4f wq = wq4[c4], wk = wk4[c4], wv = wv4[c4];   // LDS broadcast b128
        float x0 = xp[(size_t)(c4 * 4 + 0) * NN];
        float x1 = xp[(size_t)(c4 * 4 + 1) * NN];
        float x2 = xp[(size_t)(c4 * 4 + 2) * NN];
        float x3 = xp[(size_t)(c4 * 4 + 3) * NN];
        qa = fmaf(wq.x, x0, qa); ka = fmaf(wk.x, x0, ka); va = fmaf(wv.x, x0, va);
        qa = fmaf(wq.y, x1, qa); ka = fmaf(wk.y, x1, ka); va = fmaf(wv.y, x1, va);
        qa = fmaf(wq.z, x2, qa); ka = fmaf(wk.z, x2, ka); va = fmaf(wv.z, x2, va);
        qa = fmaf(wq.w, x3, qa); ka = fmaf(wk.w, x3, ka); va = fmaf(wv.w, x3, va);
    }
    __bf16 vb = (__bf16)va;
    vbh[((size_t)b * CI + i) * NN + n] = vb;
    __bf16 qb = (__bf16)qa, kb2 = (__bf16)ka;
    sq[nl * 8 + i] = *(unsigned short*)&qb;
    sk[nl * 8 + i] = *(unsigned short*)&kb2;
    __syncthreads();
    if (t < 32) {
        *(uint4*)(qbh + ((size_t)b * NN + n0 + t) * 8) = *(const uint4*)(sq + t * 8);
        *(uint4*)(kbh + ((size_t)b * NN + n0 + t) * 8) = *(const uint4*)(sk + t * 8);
    }
}

// MFMA attention, R7 structure + STAGE-STAGGERED software pipeline.
// R9 (dual chains in lockstep) gained ~0: same-stage duplication lets the
// compiler merge the lgkm waits. Here iteration k overlaps the E(k)
// ds_write->ds_read round-trip with the S-MFMAs of chunk k+1, and the k+2
// q/v prefetch sits after PV(k) (~1.5 iters of latency cover). Registers
// rotate through 2 slots; dual 72B-pitch buffers (measured 0 conflicts).
// Numerics identical to R7/R9 (absmax 0.0156).
// Grid (64 m-blocks, NSPLIT, BB) = 2048 blocks x 4 waves.
__global__ __launch_bounds__(256) void att_kernel(
        const __bf16* __restrict__ qbh, const __bf16* __restrict__ kbh,
        const __bf16* __restrict__ vbh, float* __restrict__ attab) {
    __shared__ unsigned short eld[4][2][16 * 36];  // per-wave dual bufs, 72B pitch
    const int t = threadIdx.x;
    const int w    = t >> 6;
    const int l    = t & 63;
    const int quad = l >> 4;
    const int lm   = l & 15;
    const int b  = blockIdx.z;
    const int m0 = blockIdx.x * 64 + w * 16;
    const int nbase = blockIdx.y * (NN / NSPLIT);
    const int NCH = (NN / NSPLIT) / 32;            // 32 chunks of 32 n

    bf16x8 zero8, ones8;
#pragma unroll
    for (int z = 0; z < 8; ++z) { zero8[z] = (__bf16)0.0f; ones8[z] = (__bf16)1.0f; }

    bf16x8 kfrag = zero8;                 // B[k=quad*8+j][col=lm], k<8 live
    if (quad == 0)
        kfrag = *(const bf16x8*)(kbh + ((size_t)b * NN + m0 + lm) * 8);

    const __bf16* qrow = qbh + (size_t)b * NN * 8;
    const __bf16* vrow = vbh + ((size_t)b * CI + (lm & 7)) * NN;

    unsigned short* ew0 = &eld[w][0][lm * 36];
    unsigned short* ew1 = &eld[w][1][lm * 36];

    v4f accO = {0.f, 0.f, 0.f, 0.f};

    // pipeline registers: 2 slots of (q0,q1,v)
    bf16x8 q0s[2], q1s[2], vvs[2];
    auto loadQ = [&](int nc, bf16x8& a, bf16x8& bq) {
        if (quad == 0) {
            a  = *(const bf16x8*)(qrow + (size_t)(nc + lm) * 8);
            bq = *(const bf16x8*)(qrow + (size_t)(nc + 16 + lm) * 8);
        } else { a = zero8; bq = zero8; }
    };
    auto loadV = [&](int nc, bf16x8& v) {
        if (lm < 8)       v = *(const bf16x8*)(vrow + nc + quad * 8);
        else if (lm == 8) v = ones8;
        else              v = zero8;
    };

    loadQ(nbase,      q0s[0], q1s[0]);  loadV(nbase,      vvs[0]);
    loadQ(nbase + 32, q0s[1], q1s[1]);  loadV(nbase + 32, vvs[1]);

    v4f sc0 = __builtin_amdgcn_mfma_f32_16x16x32_bf16(q0s[0], kfrag, (v4f){0.f,0.f,0.f,0.f}, 0, 0, 0);
    v4f sc1 = __builtin_amdgcn_mfma_f32_16x16x32_bf16(q1s[0], kfrag, (v4f){0.f,0.f,0.f,0.f}, 0, 0, 0);

    for (int k = 0; k < NCH; ++k) {
        const int cur = k & 1;
        unsigned short* buf = cur ? ew1 : ew0;

        // exp + pack current scores -> LDS (buf[m=lm][n_rel], 72B rows)
        bf16x4 e;
        e[0] = (__bf16)fast_exp2(sc0.x); e[1] = (__bf16)fast_exp2(sc0.y);
        e[2] = (__bf16)fast_exp2(sc0.z); e[3] = (__bf16)fast_exp2(sc0.w);
        *(bf16x4*)(buf + quad * 4) = e;
        e[0] = (__bf16)fast_exp2(sc1.x); e[1] = (__bf16)fast_exp2(sc1.y);
        e[2] = (__bf16)fast_exp2(sc1.z); e[3] = (__bf16)fast_exp2(sc1.w);
        *(bf16x4*)(buf + 16 + quad * 4) = e;

        // S-MFMAs for chunk k+1 — issue while E(k)'s LDS round-trip pends
        v4f t0 = sc0, t1 = sc1;
        if (k + 1 < NCH) {
            const int nxt = cur ^ 1;
            t0 = __builtin_amdgcn_mfma_f32_16x16x32_bf16(q0s[nxt], kfrag, (v4f){0.f,0.f,0.f,0.f}, 0, 0, 0);
            t1 = __builtin_amdgcn_mfma_f32_16x16x32_bf16(q1s[nxt], kfrag, (v4f){0.f,0.f,0.f,0.f}, 0, 0, 0);
        }

        // read E(k) as B-frag, PV accumulate
        {
            bf16x4 lo = *(const bf16x4*)(buf + quad * 8);
            bf16x4 hi = *(const bf16x4*)(buf + quad * 8 + 4);
            bf16x8 ef;
#pragma unroll
            for (int z = 0; z < 4; ++z) { ef[z] = lo[z]; ef[4 + z] = hi[z]; }
            accO = __builtin_amdgcn_mfma_f32_16x16x32_bf16(vvs[cur], ef, accO, 0, 0, 0);
        }

        // prefetch chunk k+2 into the now-free slot (needed 2 iters out)
        if (k + 2 < NCH) {
            const int nc2 = nbase + (k + 2) * 32;
            loadQ(nc2, q0s[cur], q1s[cur]);
            loadV(nc2, vvs[cur]);
        }
        sc0 = t0; sc1 = t1;
    }

    // Epilogue: D[row=quad*4+r][col=lm]; rows 0..7 = sum e*v_i, row 8 = sum e.
    float* ap = attab + (size_t)b * 9 * NN + m0 + lm;
    float av[4] = {accO.x, accO.y, accO.z, accO.w};
#pragma unroll
    for (int r = 0; r < 4; ++r) {
        int i = quad * 4 + r;
        if (i < 9) atomicAdd(ap + (size_t)i * NN, av[r]);
    }
}

// R7-proven out. Grid (NN/1024, CC, BB); block 256; float4 per thread.
__global__ __launch_bounds__(256) void out_kernel(
        const float* __restrict__ x, const float* __restrict__ Wout,
        const float* __restrict__ attab, float* __restrict__ out) {
    const int t = threadIdx.x;
    const int c = blockIdx.y;
    const int b = blockIdx.z;
    const int m = (blockIdx.x * 256 + t) * 4;
    const float* ap = attab + (size_t)b * 9 * NN + m;
    v4f sum = *(const v4f*)(ap + (size_t)8 * NN);
    v4f s = {0.f, 0.f, 0.f, 0.f};
#pragma unroll
    for (int i = 0; i < CI; ++i) {
        float wgt = Wout[c * CI + i];               // uniform -> s_load
        v4f a = *(const v4f*)(ap + (size_t)i * NN);
        s.x = fmaf(wgt, a.x, s.x);
        s.y = fmaf(wgt, a.y, s.y);
        s.z = fmaf(wgt, a.z, s.z);
        s.w = fmaf(wgt, a.w, s.w);
    }
    size_t o = ((size_t)b * CC + c) * NN + m;
    v4f xv = *(const v4f*)(x + o);
    v4f r;
    r.x = xv.x + GAMMA * (s.x / sum.x);
    r.y = xv.y + GAMMA * (s.y / sum.y);
    r.z = xv.z + GAMMA * (s.z / sum.z);
    r.w = xv.w + GAMMA * (s.w / sum.w);
    *(v4f*)(out + o) = r;
}

extern "C" void kernel_launch(void* const* d_in, const int* in_sizes, int n_in,
                              void* d_out, int out_size, void* d_ws, size_t ws_size,
                              hipStream_t stream) {
    const float* x    = (const float*)d_in[0];
    const float* Wq   = (const float*)d_in[1];
    const float* Wk   = (const float*)d_in[2];
    const float* Wv   = (const float*)d_in[3];
    const float* Wout = (const float*)d_in[4];
    float* out = (float*)d_out;

    // ws: qbh [B][N][8] bf16 | kbh [B][N][8] bf16 | vbh [B][8][N] bf16 |
    //     attab [B][9][N] fp32
    __bf16* qbh = (__bf16*)d_ws;
    __bf16* kbh = qbh + (size_t)BB * NN * 8;
    __bf16* vbh = kbh + (size_t)BB * NN * 8;
    float* attab = (float*)(vbh + (size_t)BB * NN * 8);

    qkv_kernel<<<dim3(NN / 32, BB), 256, 0, stream>>>(x, Wq, Wk, Wv, qbh, kbh, vbh, attab);
    att_kernel<<<dim3(NN / 64, NSPLIT, BB), 256, 0, stream>>>(qbh, kbh, vbh, attab);
    out_kernel<<<dim3(NN / 1024, CC, BB), 256, 0, stream>>>(x, Wout, attab, out);
}

// Round 13
// 115.263 us; speedup vs baseline: 7.2520x; 7.2520x over previous
//
#include <hip/hip_runtime.h>
#include <math.h>

#define BB 8
#define CC 64
#define NN 4096
#define CI 8
#define GAMMA 0.1f
// exp(s/sqrt(8)) = exp2(s * log2(e)/sqrt(8)); folded into k in qkv.
#define SCALE (1.44269504088896f * 0.35355339059327f)
#define NSPLIT 4

typedef float v4f __attribute__((ext_vector_type(4)));
typedef __bf16 bf16x8 __attribute__((ext_vector_type(8)));
typedef __bf16 bf16x4 __attribute__((ext_vector_type(4)));

__device__ __forceinline__ float fast_exp2(float x) {
    return __builtin_amdgcn_exp2f(x);
}

// R7-proven qkv. Grid (NN/32, BB); block 256 = 8 i-groups x 32 n.
// qbh[b][n][8], kbh[b][m][8] (k*SCALE), vbh[b][i][N] bf16; zeros attab[b][9][N].
__global__ __launch_bounds__(256) void qkv_kernel(
        const float* __restrict__ x,
        const float* __restrict__ Wq, const float* __restrict__ Wk,
        const float* __restrict__ Wv,
        __bf16* __restrict__ qbh, __bf16* __restrict__ kbh,
        __bf16* __restrict__ vbh, float* __restrict__ attab) {
    __shared__ float sw[3 * CI * CC];     // 6 KB: Wq | Wk*SCALE | Wv
    __shared__ unsigned short sq[32 * 8]; // bf16 tile [n_local][i]
    __shared__ unsigned short sk[32 * 8];
    const int t = threadIdx.x;
    const int i  = t >> 5;
    const int nl = t & 31;
    const int b  = blockIdx.y;
    const int n0 = blockIdx.x * 32;

    for (int idx = t; idx < CI * CC; idx += 256) {
        sw[idx]                = Wq[idx];
        sw[CI * CC + idx]      = Wk[idx] * SCALE;
        sw[2 * CI * CC + idx]  = Wv[idx];
    }
    int lin = (blockIdx.y * (NN / 32) + blockIdx.x) * 256 + t;
    for (int idx = lin; idx < BB * 9 * NN; idx += BB * NN * CI) attab[idx] = 0.f;
    __syncthreads();

    const int n = n0 + nl;
    const float* xp = x + ((size_t)b * CC) * NN + n;
    const v4f* wq4 = (const v4f*)(sw + i * CC);
    const v4f* wk4 = (const v4f*)(sw + CI * CC + i * CC);
    const v4f* wv4 = (const v4f*)(sw + 2 * CI * CC + i * CC);
    float qa = 0.f, ka = 0.f, va = 0.f;
#pragma unroll 4
    for (int c4 = 0; c4 < CC / 4; ++c4) {
        v4f wq = wq4[c4], wk = wk4[c4], wv = wv4[c4];   // LDS broadcast b128
        float x0 = xp[(size_t)(c4 * 4 + 0) * NN];
        float x1 = xp[(size_t)(c4 * 4 + 1) * NN];
        float x2 = xp[(size_t)(c4 * 4 + 2) * NN];
        float x3 = xp[(size_t)(c4 * 4 + 3) * NN];
        qa = fmaf(wq.x, x0, qa); ka = fmaf(wk.x, x0, ka); va = fmaf(wv.x, x0, va);
        qa = fmaf(wq.y, x1, qa); ka = fmaf(wk.y, x1, ka); va = fmaf(wv.y, x1, va);
        qa = fmaf(wq.z, x2, qa); ka = fmaf(wk.z, x2, ka); va = fmaf(wv.z, x2, va);
        qa = fmaf(wq.w, x3, qa); ka = fmaf(wk.w, x3, ka); va = fmaf(wv.w, x3, va);
    }
    __bf16 vb = (__bf16)va;
    vbh[((size_t)b * CI + i) * NN + n] = vb;
    __bf16 qb = (__bf16)qa, kb2 = (__bf16)ka;
    sq[nl * 8 + i] = *(unsigned short*)&qb;
    sk[nl * 8 + i] = *(unsigned short*)&kb2;
    __syncthreads();
    if (t < 32) {
        *(uint4*)(qbh + ((size_t)b * NN + n0 + t) * 8) = *(const uint4*)(sq + t * 8);
        *(uint4*)(kbh + ((size_t)b * NN + n0 + t) * 8) = *(const uint4*)(sk + t * 8);
    }
}

// MFMA attention, stage-staggered pipeline — R12's schedule with R12's
// codegen bug removed: NAMED slots (no dynamically-indexed register arrays),
// branchless 2x-unrolled body (k+2 prefetch deliberately overruns into ws
// scratch — values never consumed; d_ws is ~268MB, reads are in-bounds).
// Schedule per half-body: exp/write E(k) -> S-MFMA(k+1) (covers E's LDS
// round-trip) -> PV(k) -> prefetch(k+2) (covers load latency).
// Numerics identical to R7/R8 (absmax 0.0156).
// Grid (64 m-blocks, NSPLIT, BB) = 2048 blocks x 4 waves.
__global__ __launch_bounds__(256) void att_kernel(
        const __bf16* __restrict__ qbh, const __bf16* __restrict__ kbh,
        const __bf16* __restrict__ vbh, float* __restrict__ attab) {
    __shared__ unsigned short eld[4][2][16 * 36];  // per-wave dual bufs, 72B pitch
    const int t = threadIdx.x;
    const int w    = t >> 6;
    const int l    = t & 63;
    const int quad = l >> 4;
    const int lm   = l & 15;
    const int b  = blockIdx.z;
    const int m0 = blockIdx.x * 64 + w * 16;
    const int nbase = blockIdx.y * (NN / NSPLIT);
    const int NCH = (NN / NSPLIT) / 32;            // 32 chunks of 32 n

    bf16x8 zero8, ones8;
#pragma unroll
    for (int z = 0; z < 8; ++z) { zero8[z] = (__bf16)0.0f; ones8[z] = (__bf16)1.0f; }

    bf16x8 kfrag = zero8;                 // B[k=quad*8+j][col=lm], k<8 live
    if (quad == 0)
        kfrag = *(const bf16x8*)(kbh + ((size_t)b * NN + m0 + lm) * 8);

    const __bf16* qrow = qbh + (size_t)b * NN * 8;
    const __bf16* vrow = vbh + ((size_t)b * CI + (lm & 7)) * NN;
    const bool q_on = (quad == 0);
    const bool v_v  = (lm < 8);
    const bool v_1  = (lm == 8);

    unsigned short* ew0 = &eld[w][0][lm * 36];
    unsigned short* ew1 = &eld[w][1][lm * 36];

    v4f accO = {0.f, 0.f, 0.f, 0.f};

    // ---- named pipeline slots ----
    bf16x8 q0a, q1a, va_, q0b, q1b, vb_;
    {
        const int nc = nbase;
        q0a = q_on ? *(const bf16x8*)(qrow + (size_t)(nc + lm) * 8) : zero8;
        q1a = q_on ? *(const bf16x8*)(qrow + (size_t)(nc + 16 + lm) * 8) : zero8;
        va_ = v_v ? *(const bf16x8*)(vrow + nc + quad * 8) : (v_1 ? ones8 : zero8);
    }
    {
        const int nc = nbase + 32;
        q0b = q_on ? *(const bf16x8*)(qrow + (size_t)(nc + lm) * 8) : zero8;
        q1b = q_on ? *(const bf16x8*)(qrow + (size_t)(nc + 16 + lm) * 8) : zero8;
        vb_ = v_v ? *(const bf16x8*)(vrow + nc + quad * 8) : (v_1 ? ones8 : zero8);
    }

    v4f sc0 = __builtin_amdgcn_mfma_f32_16x16x32_bf16(q0a, kfrag, (v4f){0.f,0.f,0.f,0.f}, 0, 0, 0);
    v4f sc1 = __builtin_amdgcn_mfma_f32_16x16x32_bf16(q1a, kfrag, (v4f){0.f,0.f,0.f,0.f}, 0, 0, 0);

    for (int k = 0; k < NCH; k += 2) {
        // ======== even half: current slot A, buffer ew0 ========
        bf16x4 e;
        e[0] = (__bf16)fast_exp2(sc0.x); e[1] = (__bf16)fast_exp2(sc0.y);
        e[2] = (__bf16)fast_exp2(sc0.z); e[3] = (__bf16)fast_exp2(sc0.w);
        *(bf16x4*)(ew0 + quad * 4) = e;
        e[0] = (__bf16)fast_exp2(sc1.x); e[1] = (__bf16)fast_exp2(sc1.y);
        e[2] = (__bf16)fast_exp2(sc1.z); e[3] = (__bf16)fast_exp2(sc1.w);
        *(bf16x4*)(ew0 + 16 + quad * 4) = e;

        v4f t0 = __builtin_amdgcn_mfma_f32_16x16x32_bf16(q0b, kfrag, (v4f){0.f,0.f,0.f,0.f}, 0, 0, 0);
        v4f t1 = __builtin_amdgcn_mfma_f32_16x16x32_bf16(q1b, kfrag, (v4f){0.f,0.f,0.f,0.f}, 0, 0, 0);

        {
            bf16x4 lo = *(const bf16x4*)(ew0 + quad * 8);
            bf16x4 hi = *(const bf16x4*)(ew0 + quad * 8 + 4);
            bf16x8 ef;
#pragma unroll
            for (int z = 0; z < 4; ++z) { ef[z] = lo[z]; ef[4 + z] = hi[z]; }
            accO = __builtin_amdgcn_mfma_f32_16x16x32_bf16(va_, ef, accO, 0, 0, 0);
        }
        {   // prefetch chunk k+2 into slot A (overrun-safe, branchless)
            const int nc = nbase + (k + 2) * 32;
            q0a = q_on ? *(const bf16x8*)(qrow + (size_t)(nc + lm) * 8) : zero8;
            q1a = q_on ? *(const bf16x8*)(qrow + (size_t)(nc + 16 + lm) * 8) : zero8;
            va_ = v_v ? *(const bf16x8*)(vrow + nc + quad * 8) : (v_1 ? ones8 : zero8);
        }
        sc0 = t0; sc1 = t1;

        // ======== odd half: current slot B, buffer ew1 ========
        e[0] = (__bf16)fast_exp2(sc0.x); e[1] = (__bf16)fast_exp2(sc0.y);
        e[2] = (__bf16)fast_exp2(sc0.z); e[3] = (__bf16)fast_exp2(sc0.w);
        *(bf16x4*)(ew1 + quad * 4) = e;
        e[0] = (__bf16)fast_exp2(sc1.x); e[1] = (__bf16)fast_exp2(sc1.y);
        e[2] = (__bf16)fast_exp2(sc1.z); e[3] = (__bf16)fast_exp2(sc1.w);
        *(bf16x4*)(ew1 + 16 + quad * 4) = e;

        t0 = __builtin_amdgcn_mfma_f32_16x16x32_bf16(q0a, kfrag, (v4f){0.f,0.f,0.f,0.f}, 0, 0, 0);
        t1 = __builtin_amdgcn_mfma_f32_16x16x32_bf16(q1a, kfrag, (v4f){0.f,0.f,0.f,0.f}, 0, 0, 0);

        {
            bf16x4 lo = *(const bf16x4*)(ew1 + quad * 8);
            bf16x4 hi = *(const bf16x4*)(ew1 + quad * 8 + 4);
            bf16x8 ef;
#pragma unroll
            for (int z = 0; z < 4; ++z) { ef[z] = lo[z]; ef[4 + z] = hi[z]; }
            accO = __builtin_amdgcn_mfma_f32_16x16x32_bf16(vb_, ef, accO, 0, 0, 0);
        }
        {   // prefetch chunk k+3 into slot B (overrun-safe, branchless)
            const int nc = nbase + (k + 3) * 32;
            q0b = q_on ? *(const bf16x8*)(qrow + (size_t)(nc + lm) * 8) : zero8;
            q1b = q_on ? *(const bf16x8*)(qrow + (size_t)(nc + 16 + lm) * 8) : zero8;
            vb_ = v_v ? *(const bf16x8*)(vrow + nc + quad * 8) : (v_1 ? ones8 : zero8);
        }
        sc0 = t0; sc1 = t1;
    }

    // Epilogue: D[row=quad*4+r][col=lm]; rows 0..7 = sum e*v_i, row 8 = sum e.
    float* ap = attab + (size_t)b * 9 * NN + m0 + lm;
    float av[4] = {accO.x, accO.y, accO.z, accO.w};
#pragma unroll
    for (int r = 0; r < 4; ++r) {
        int i = quad * 4 + r;
        if (i < 9) atomicAdd(ap + (size_t)i * NN, av[r]);
    }
}

// R7-proven out. Grid (NN/1024, CC, BB); block 256; float4 per thread.
__global__ __launch_bounds__(256) void out_kernel(
        const float* __restrict__ x, const float* __restrict__ Wout,
        const float* __restrict__ attab, float* __restrict__ out) {
    const int t = threadIdx.x;
    const int c = blockIdx.y;
    const int b = blockIdx.z;
    const int m = (blockIdx.x * 256 + t) * 4;
    const float* ap = attab + (size_t)b * 9 * NN + m;
    v4f sum = *(const v4f*)(ap + (size_t)8 * NN);
    v4f s = {0.f, 0.f, 0.f, 0.f};
#pragma unroll
    for (int i = 0; i < CI; ++i) {
        float wgt = Wout[c * CI + i];               // uniform -> s_load
        v4f a = *(const v4f*)(ap + (size_t)i * NN);
        s.x = fmaf(wgt, a.x, s.x);
        s.y = fmaf(wgt, a.y, s.y);
        s.z = fmaf(wgt, a.z, s.z);
        s.w = fmaf(wgt, a.w, s.w);
    }
    size_t o = ((size_t)b * CC + c) * NN + m;
    v4f xv = *(const v4f*)(x + o);
    v4f r;
    r.x = xv.x + GAMMA * (s.x / sum.x);
    r.y = xv.y + GAMMA * (s.y / sum.y);
    r.z = xv.z + GAMMA * (s.z / sum.z);
    r.w = xv.w + GAMMA * (s.w / sum.w);
    *(v4f*)(out + o) = r;
}

extern "C" void kernel_launch(void* const* d_in, const int* in_sizes, int n_in,
                              void* d_out, int out_size, void* d_ws, size_t ws_size,
                              hipStream_t stream) {
    const float* x    = (const float*)d_in[0];
    const float* Wq   = (const float*)d_in[1];
    const float* Wk   = (const float*)d_in[2];
    const float* Wv   = (const float*)d_in[3];
    const float* Wout = (const float*)d_in[4];
    float* out = (float*)d_out;

    // ws: qbh [B][N][8] bf16 | kbh [B][N][8] bf16 | vbh [B][8][N] bf16 |
    //     attab [B][9][N] fp32
    __bf16* qbh = (__bf16*)d_ws;
    __bf16* kbh = qbh + (size_t)BB * NN * 8;
    __bf16* vbh = kbh + (size_t)BB * NN * 8;
    float* attab = (float*)(vbh + (size_t)BB * NN * 8);

    qkv_kernel<<<dim3(NN / 32, BB), 256, 0, stream>>>(x, Wq, Wk, Wv, qbh, kbh, vbh, attab);
    att_kernel<<<dim3(NN / 64, NSPLIT, BB), 256, 0, stream>>>(qbh, kbh, vbh, attab);
    out_kernel<<<dim3(NN / 1024, CC, BB), 256, 0, stream>>>(x, Wout, attab, out);
}

// Round 14
// 113.531 us; speedup vs baseline: 7.3626x; 1.0153x over previous
//
#include <hip/hip_runtime.h>
#include <math.h>

#define BB 8
#define CC 64
#define NN 4096
#define CI 8
#define GAMMA 0.1f
// exp(s/sqrt(8)) = exp2(s * log2(e)/sqrt(8)); folded into k in qkv.
#define SCALE (1.44269504088896f * 0.35355339059327f)
#define NSPLIT 8

typedef float v4f  __attribute__((ext_vector_type(4)));
typedef float v16f __attribute__((ext_vector_type(16)));
typedef __bf16 bf16x8 __attribute__((ext_vector_type(8)));
typedef __bf16 bf16x4 __attribute__((ext_vector_type(4)));

__device__ __forceinline__ float fast_exp2(float x) {
    return __builtin_amdgcn_exp2f(x);
}

// R7-proven qkv. Grid (NN/32, BB); block 256 = 8 i-groups x 32 n.
// qbh[b][n][8], kbh[b][m][8] (k*SCALE), vbh[b][i][N] bf16; zeros attab[b][9][N].
__global__ __launch_bounds__(256) void qkv_kernel(
        const float* __restrict__ x,
        const float* __restrict__ Wq, const float* __restrict__ Wk,
        const float* __restrict__ Wv,
        __bf16* __restrict__ qbh, __bf16* __restrict__ kbh,
        __bf16* __restrict__ vbh, float* __restrict__ attab) {
    __shared__ float sw[3 * CI * CC];     // 6 KB: Wq | Wk*SCALE | Wv
    __shared__ unsigned short sq[32 * 8]; // bf16 tile [n_local][i]
    __shared__ unsigned short sk[32 * 8];
    const int t = threadIdx.x;
    const int i  = t >> 5;
    const int nl = t & 31;
    const int b  = blockIdx.y;
    const int n0 = blockIdx.x * 32;

    for (int idx = t; idx < CI * CC; idx += 256) {
        sw[idx]                = Wq[idx];
        sw[CI * CC + idx]      = Wk[idx] * SCALE;
        sw[2 * CI * CC + idx]  = Wv[idx];
    }
    int lin = (blockIdx.y * (NN / 32) + blockIdx.x) * 256 + t;
    for (int idx = lin; idx < BB * 9 * NN; idx += BB * NN * CI) attab[idx] = 0.f;
    __syncthreads();

    const int n = n0 + nl;
    const float* xp = x + ((size_t)b * CC) * NN + n;
    const v4f* wq4 = (const v4f*)(sw + i * CC);
    const v4f* wk4 = (const v4f*)(sw + CI * CC + i * CC);
    const v4f* wv4 = (const v4f*)(sw + 2 * CI * CC + i * CC);
    float qa = 0.f, ka = 0.f, va = 0.f;
#pragma unroll 4
    for (int c4 = 0; c4 < CC / 4; ++c4) {
        v4f wq = wq4[c4], wk = wk4[c4], wv = wv4[c4];   // LDS broadcast b128
        float x0 = xp[(size_t)(c4 * 4 + 0) * NN];
        float x1 = xp[(size_t)(c4 * 4 + 1) * NN];
        float x2 = xp[(size_t)(c4 * 4 + 2) * NN];
        float x3 = xp[(size_t)(c4 * 4 + 3) * NN];
        qa = fmaf(wq.x, x0, qa); ka = fmaf(wk.x, x0, ka); va = fmaf(wv.x, x0, va);
        qa = fmaf(wq.y, x1, qa); ka = fmaf(wk.y, x1, ka); va = fmaf(wv.y, x1, va);
        qa = fmaf(wq.z, x2, qa); ka = fmaf(wk.z, x2, ka); va = fmaf(wv.z, x2, va);
        qa = fmaf(wq.w, x3, qa); ka = fmaf(wk.w, x3, ka); va = fmaf(wv.w, x3, va);
    }
    __bf16 vb = (__bf16)va;
    vbh[((size_t)b * CI + i) * NN + n] = vb;
    __bf16 qb = (__bf16)qa, kb2 = (__bf16)ka;
    sq[nl * 8 + i] = *(unsigned short*)&qb;
    sk[nl * 8 + i] = *(unsigned short*)&kb2;
    __syncthreads();
    if (t < 32) {
        *(uint4*)(qbh + ((size_t)b * NN + n0 + t) * 8) = *(const uint4*)(sq + t * 8);
        *(uint4*)(kbh + ((size_t)b * NN + n0 + t) * 8) = *(const uint4*)(sk + t * 8);
    }
}

// 32x32-tile MFMA attention. Structural change vs R7/R13 (three schedules all
// measured 42-43us -> scheduling is compiler-neutralized; change the work
// instead): S via ONE v_mfma_f32_32x32x16_bf16 per 32n x 32m (K=16, half
// waste vs 3/4; replaces four 16x16x32), E-transposes per unit 2 -> 1
// (chain count halves), PV = two 16x16x32 sharing one v-fragment.
// S C-layout (HW-verified): col=lane&31, row=(reg&3)+8*(reg>>2)+4*(lane>>5).
// Lane writes its 16 E values as 4x ds_write_b64 runs into a per-wave
// [32 m][36 hw] tile (72B pitch - the pitch measured at 0 conflicts);
// PV B-frags read rows lm / 16+lm at hw offset quad*8 (R7-proven pattern).
// A-frags: A[row=lane&31][k=(lane>>5)*8+j] (same pattern family as the
// verified 16x16x32 k=(lane>>4)*8+j). |scores| < ~2 -> exp without
// max-subtraction safe. NSPLIT=8 keeps 8192 waves (8/SIMD).
// Grid (NN/128, NSPLIT, BB) = 2048 blocks x 4 waves; wave = 32-m tile.
__global__ __launch_bounds__(256) void att_kernel(
        const __bf16* __restrict__ qbh, const __bf16* __restrict__ kbh,
        const __bf16* __restrict__ vbh, float* __restrict__ attab) {
    __shared__ unsigned short eld[4][32 * 36];  // per-wave tile, 72B pitch, 9216B
    const int t = threadIdx.x;
    const int w    = t >> 6;
    const int l    = t & 63;
    const int ln   = l & 31;        // S: A-row (n) / B-col (m); C col (m)
    const int hi   = l >> 5;        // S: k-half selector (k = hi*8 + j)
    const int quad = l >> 4;        // PV: 16x16 quadrant
    const int lm   = l & 15;
    const int b  = blockIdx.z;
    const int m0 = blockIdx.x * 128 + w * 32;
    const int nbase = blockIdx.y * (NN / NSPLIT);   // 512 per wave
    const int NCH = (NN / NSPLIT) / 32;             // 16 chunks of 32 n

    bf16x8 zero8, ones8;
#pragma unroll
    for (int z = 0; z < 8; ++z) { zero8[z] = (__bf16)0.0f; ones8[z] = (__bf16)1.0f; }

    // S B-frag (loop-invariant): B[k=hi*8+j][col=ln] = K[m0+ln][j], hi==0 live
    bf16x8 kfragB = hi ? zero8
                       : *(const bf16x8*)(kbh + ((size_t)b * NN + m0 + ln) * 8);

    const __bf16* qrow = qbh + (size_t)b * NN * 8;
    const __bf16* vrow = vbh + ((size_t)b * CI + (lm & 7)) * NN;
    const bool v_v = (lm < 8);
    const bool v_1 = (lm == 8);

    unsigned short* tile = eld[w];
    unsigned short* wr   = tile + ln * 36 + hi * 4;   // write base for this lane
    const unsigned short* rd0 = tile + lm * 36 + quad * 8;
    const unsigned short* rd1 = tile + (16 + lm) * 36 + quad * 8;

    v4f acc0 = {0.f, 0.f, 0.f, 0.f};
    v4f acc1 = {0.f, 0.f, 0.f, 0.f};

    for (int ch = 0; ch < NCH; ++ch) {
        const int nc = nbase + ch * 32;
        // S A-frag: A[row=ln][k=hi*8+j] = Q[nc+ln][j], hi==0 live
        bf16x8 qfrag = hi ? zero8
                          : *(const bf16x8*)(qrow + (size_t)(nc + ln) * 8);
        // PV A-frag: A[row=lm][k=quad*8+j] = v_i[nc+quad*8+j] | ones | zero
        bf16x8 vfrag = v_v ? *(const bf16x8*)(vrow + nc + quad * 8)
                           : (v_1 ? ones8 : zero8);

        v16f S = __builtin_amdgcn_mfma_f32_32x32x16_bf16(
            qfrag, kfragB,
            (v16f){0.f,0.f,0.f,0.f,0.f,0.f,0.f,0.f,0.f,0.f,0.f,0.f,0.f,0.f,0.f,0.f},
            0, 0, 0);

        // E: reg r -> n_local = (r&3) + 8*(r>>2) + 4*hi, col m = m0+ln.
        // Write 4 runs of 4 (ds_write_b64) into tile[m=ln][n]:
#pragma unroll
        for (int g = 0; g < 4; ++g) {
            bf16x4 e;
            e[0] = (__bf16)fast_exp2(S[4 * g + 0]);
            e[1] = (__bf16)fast_exp2(S[4 * g + 1]);
            e[2] = (__bf16)fast_exp2(S[4 * g + 2]);
            e[3] = (__bf16)fast_exp2(S[4 * g + 3]);
            *(bf16x4*)(wr + g * 8) = e;
        }

        // PV B-frags: B[k=quad*8+j][col=lm] = tile[m_half][quad*8+j]
        bf16x8 ef0 = *(const bf16x8*)(rd0);
        bf16x8 ef1 = *(const bf16x8*)(rd1);
        acc0 = __builtin_amdgcn_mfma_f32_16x16x32_bf16(vfrag, ef0, acc0, 0, 0, 0);
        acc1 = __builtin_amdgcn_mfma_f32_16x16x32_bf16(vfrag, ef1, acc1, 0, 0, 0);
    }

    // Epilogue: D[row=quad*4+r][col=lm]; rows 0..7 = sum e*v_i, row 8 = sum e.
    float* ap = attab + (size_t)b * 9 * NN + m0;
    float a0[4] = {acc0.x, acc0.y, acc0.z, acc0.w};
    float a1[4] = {acc1.x, acc1.y, acc1.z, acc1.w};
#pragma unroll
    for (int r = 0; r < 4; ++r) {
        int i = quad * 4 + r;
        if (i < 9) {
            atomicAdd(ap + (size_t)i * NN + lm, a0[r]);
            atomicAdd(ap + (size_t)i * NN + 16 + lm, a1[r]);
        }
    }
}

// R7-proven out. Grid (NN/1024, CC, BB); block 256; float4 per thread.
__global__ __launch_bounds__(256) void out_kernel(
        const float* __restrict__ x, const float* __restrict__ Wout,
        const float* __restrict__ attab, float* __restrict__ out) {
    const int t = threadIdx.x;
    const int c = blockIdx.y;
    const int b = blockIdx.z;
    const int m = (blockIdx.x * 256 + t) * 4;
    const float* ap = attab + (size_t)b * 9 * NN + m;
    v4f sum = *(const v4f*)(ap + (size_t)8 * NN);
    v4f s = {0.f, 0.f, 0.f, 0.f};
#pragma unroll
    for (int i = 0; i < CI; ++i) {
        float wgt = Wout[c * CI + i];               // uniform -> s_load
        v4f a = *(const v4f*)(ap + (size_t)i * NN);
        s.x = fmaf(wgt, a.x, s.x);
        s.y = fmaf(wgt, a.y, s.y);
        s.z = fmaf(wgt, a.z, s.z);
        s.w = fmaf(wgt, a.w, s.w);
    }
    size_t o = ((size_t)b * CC + c) * NN + m;
    v4f xv = *(const v4f*)(x + o);
    v4f r;
    r.x = xv.x + GAMMA * (s.x / sum.x);
    r.y = xv.y + GAMMA * (s.y / sum.y);
    r.z = xv.z + GAMMA * (s.z / sum.z);
    r.w = xv.w + GAMMA * (s.w / sum.w);
    *(v4f*)(out + o) = r;
}

extern "C" void kernel_launch(void* const* d_in, const int* in_sizes, int n_in,
                              void* d_out, int out_size, void* d_ws, size_t ws_size,
                              hipStream_t stream) {
    const float* x    = (const float*)d_in[0];
    const float* Wq   = (const float*)d_in[1];
    const float* Wk   = (const float*)d_in[2];
    const float* Wv   = (const float*)d_in[3];
    const float* Wout = (const float*)d_in[4];
    float* out = (float*)d_out;

    // ws: qbh [B][N][8] bf16 | kbh [B][N][8] bf16 | vbh [B][8][N] bf16 |
    //     attab [B][9][N] fp32
    __bf16* qbh = (__bf16*)d_ws;
    __bf16* kbh = qbh + (size_t)BB * NN * 8;
    __bf16* vbh = kbh + (size_t)BB * NN * 8;
    float* attab = (float*)(vbh + (size_t)BB * NN * 8);

    qkv_kernel<<<dim3(NN / 32, BB), 256, 0, stream>>>(x, Wq, Wk, Wv, qbh, kbh, vbh, attab);
    att_kernel<<<dim3(NN / 128, NSPLIT, BB), 256, 0, stream>>>(qbh, kbh, vbh, attab);
    out_kernel<<<dim3(NN / 1024, CC, BB), 256, 0, stream>>>(x, Wout, attab, out);
}